// Round 4
// baseline (490.182 us; speedup 1.0000x reference)
//
#include <hip/hip_runtime.h>
#include <hip/hip_bf16.h>
#include <cstdint>
#include <cstddef>

// ---------------- types / helpers ----------------
typedef float  f32x4  __attribute__((ext_vector_type(4)));
typedef __bf16 bf16x8 __attribute__((ext_vector_type(8)));
typedef unsigned short u16x8 __attribute__((ext_vector_type(8)));

__device__ __forceinline__ unsigned short f2bf(float f) {
    unsigned u = __float_as_uint(f);
    u += 0x7FFFu + ((u >> 16) & 1u);   // round-to-nearest-even
    return (unsigned short)(u >> 16);
}

// ---------------- problem constants ----------------
// B=64, C=80, IN_CH=300, J=8192, S=8, OUT=1024
// feature [64,2048,14,14] (131072 rows of 196), out [64,80]

// ---------------- ws layout (bytes) ----------------
constexpr size_t OFF_FEATB = 0;          // 64*2048 bf16  = 262144
constexpr size_t OFF_ADJ   = 262144;     // 80*80 f32     = 25600
constexpr size_t OFF_Y0    = 287744;     // 80*1024 f32   = 327680
constexpr size_t OFF_X1    = 615424;     // 80*1024 f32   = 327680
constexpr size_t OFF_X2B   = 943104;     // 80*1024 bf16  = 163840
constexpr size_t OFF_WG2T  = 1106944;    // 2048*1024 f32 = 8388608
constexpr size_t OFF_XB    = 9495552;    // 80*2048 bf16  = 327680
constexpr size_t OFF_IMG   = 9823232;    // 64*8192 f32   = 2097152
constexpr size_t OFF_CLS   = 11920384;   // 80*8192 f32   = 2621440
constexpr size_t OFF_G     = 14541824;   // 80*8192 f32   = 2621440
constexpr size_t OFF_CNT   = 17163264;   // 4 bytes barrier counter

// ---------------- grid-wide barrier ----------------
// Grid = 256 blocks, __launch_bounds__(512,2), LDS 80KB -> every CU can hold
// >=1 block, total capacity >= grid, so all blocks are co-resident: spin is safe.
__device__ __forceinline__ void grid_barrier(unsigned* cnt, unsigned target) {
    __syncthreads();
    if (threadIdx.x == 0) {
        __threadfence();   // agent-scope release: flush dirty L2 to coherent point
        __hip_atomic_fetch_add(cnt, 1u, __ATOMIC_ACQ_REL, __HIP_MEMORY_SCOPE_AGENT);
        while (__hip_atomic_load(cnt, __ATOMIC_ACQUIRE, __HIP_MEMORY_SCOPE_AGENT) < target)
            __builtin_amdgcn_s_sleep(2);
        __threadfence();   // acquire side
    }
    __syncthreads();
}

// =================== roles (device functions) ===================

// maxpool: 16 lanes per row, 4 rows per wave, 128 rows per virtual bid.
__device__ __forceinline__ void maxpool_role(int vbid, const float* __restrict__ feature,
                                             unsigned short* __restrict__ featb) {
    int wave = threadIdx.x >> 6, lane = threadIdx.x & 63;
    int r = lane >> 4, q = lane & 15;
    #pragma unroll
    for (int it = 0; it < 4; ++it) {
        int row = vbid * 128 + it * 32 + wave * 4 + r;
        const float4* p = (const float4*)(feature + (size_t)row * 196);
        float4 a = p[q], b = p[q + 16], c = p[q + 32];
        float m = fmaxf(fmaxf(fmaxf(a.x, a.y), fmaxf(a.z, a.w)),
                 fmaxf(fmaxf(fmaxf(b.x, b.y), fmaxf(b.z, b.w)),
                       fmaxf(fmaxf(c.x, c.y), fmaxf(c.z, c.w))));
        if (q == 0) {                       // tail float4 (indices 192..195)
            float4 d = p[48];
            m = fmaxf(m, fmaxf(fmaxf(d.x, d.y), fmaxf(d.z, d.w)));
        }
        #pragma unroll
        for (int off = 1; off < 16; off <<= 1) m = fmaxf(m, __shfl_xor(m, off));
        if (q == 0) featb[row] = f2bf(m);
    }
}

// skinny GEMM role: out[c, jh*512 + jq*4 ..] = sum_k X[c,k] * W[k, j]  (N=1024)
// 512 threads = 4 k-slices x 128 j-float4; LDS reduce across slices.
template <int KS>   // slice length (K = 4*KS)
__device__ __forceinline__ void skinny_role(int idx, const float* __restrict__ X,
                                            const float* __restrict__ W,
                                            float* __restrict__ outf,
                                            unsigned short* __restrict__ outb,
                                            int leaky, float4* red /* [4*128] */) {
    int c = idx >> 1, jh = idx & 1;
    int t = threadIdx.x;
    int jq = t & 127, ks = t >> 7;
    int j = jh * 512 + jq * 4;
    const float* xr = X + c * 4 * KS + ks * KS;
    const float* wp = W + (size_t)(ks * KS) * 1024 + j;
    float4 acc = {0.f, 0.f, 0.f, 0.f};
    #pragma unroll 5
    for (int k = 0; k < KS; k++) {
        float a = xr[k];
        float4 w = *(const float4*)(wp + (size_t)k * 1024);
        acc.x = fmaf(a, w.x, acc.x);
        acc.y = fmaf(a, w.y, acc.y);
        acc.z = fmaf(a, w.z, acc.z);
        acc.w = fmaf(a, w.w, acc.w);
    }
    red[ks * 128 + jq] = acc;
    __syncthreads();
    if (ks == 0) {
        float4 s0 = red[jq], s1 = red[128 + jq], s2 = red[256 + jq], s3 = red[384 + jq];
        float4 s;
        s.x = s0.x + s1.x + s2.x + s3.x;
        s.y = s0.y + s1.y + s2.y + s3.y;
        s.z = s0.z + s1.z + s2.z + s3.z;
        s.w = s0.w + s1.w + s2.w + s3.w;
        if (leaky) {
            if (s.x < 0.f) s.x *= 0.2f;
            if (s.y < 0.f) s.y *= 0.2f;
            if (s.z < 0.f) s.z *= 0.2f;
            if (s.w < 0.f) s.w *= 0.2f;
        }
        size_t o = (size_t)c * 1024 + j;
        if (outf) *(float4*)(outf + o) = s;
        if (outb) {
            unsigned short b4[4] = {f2bf(s.x), f2bf(s.y), f2bf(s.z), f2bf(s.w)};
            *(uint64_t*)(outb + o) = *(const uint64_t*)b4;
        }
    }
    __syncthreads();   // red reused by caller afterwards
}

// transpose W_gc2 [1024][2048] -> wg2t [2048][1024], 64x64 tiles, 512 threads
__device__ __forceinline__ void transpose_role(int idx, const float* __restrict__ in,
                                               float* __restrict__ out, float* t /*64*65*/) {
    int c0 = (idx & 31) * 64, r0 = (idx >> 5) * 64;
    int tx = threadIdx.x & 63, ty = threadIdx.x >> 6;   // 64 x 8
    #pragma unroll
    for (int i = 0; i < 64; i += 8)
        t[(ty + i) * 65 + tx] = in[(size_t)(r0 + ty + i) * 2048 + c0 + tx];
    __syncthreads();
    #pragma unroll
    for (int i = 0; i < 64; i += 8)
        out[(size_t)(c0 + ty + i) * 1024 + r0 + tx] = t[tx * 65 + (ty + i)];
}

// adj[i,j] = A[j,i] * dinv[i] * dinv[j]
__device__ __forceinline__ void adj_role(const float* __restrict__ A, float* __restrict__ adjp,
                                         float* dinv /* >=80 floats LDS */) {
    int t = threadIdx.x;
    if (t < 80) {
        const float4* ar = (const float4*)(A + t * 80);
        float4 s4 = {0.f, 0.f, 0.f, 0.f};
        #pragma unroll
        for (int j = 0; j < 20; j++) {
            float4 v = ar[j];
            s4.x += v.x; s4.y += v.y; s4.z += v.z; s4.w += v.w;
        }
        dinv[t] = 1.0f / sqrtf(s4.x + s4.y + s4.z + s4.w);
    }
    __syncthreads();
    for (int i = t; i < 6400; i += 512) {
        int r = i / 80, cc = i % 80;
        adjp[i] = A[cc * 80 + r] * dinv[r] * dinv[cc];
    }
}

// MFMA GEMM with in-block K-split: out[m,n] = sum_k X[m,k]*W[n,k] (+bias[n])
// block = 8 waves: 2 n-frags x 4 k-splits; BN=32; LDS reduce; f32/bf16 out.
template <int MF>
__device__ __forceinline__ void gemm_block(int bx, const unsigned short* __restrict__ X,
                                           const float* __restrict__ W,
                                           const float* __restrict__ bias,
                                           float* __restrict__ outf,
                                           unsigned short* __restrict__ outb,
                                           int N, int K, float (*red)[64][21]) {
    int tid = threadIdx.x;
    int wave = tid >> 6, lane = tid & 63;
    int nf = wave & 1, ks = wave >> 1;
    int n = bx * 32 + nf * 16 + (lane & 15);
    int rowa = lane & 15;
    int koff = (lane >> 4) * 8;
    int Kc = K >> 2;
    int k0 = ks * Kc;

    f32x4 acc[MF];
    #pragma unroll
    for (int i = 0; i < MF; i++) acc[i] = (f32x4)(0.f);

    const float* wrow = W + (size_t)n * K;

    #pragma unroll 2
    for (int k = k0; k < k0 + Kc; k += 32) {
        float4 w0 = *(const float4*)(wrow + k + koff);
        float4 w1 = *(const float4*)(wrow + k + koff + 4);
        u16x8 bu;
        bu[0] = f2bf(w0.x); bu[1] = f2bf(w0.y); bu[2] = f2bf(w0.z); bu[3] = f2bf(w0.w);
        bu[4] = f2bf(w1.x); bu[5] = f2bf(w1.y); bu[6] = f2bf(w1.z); bu[7] = f2bf(w1.w);
        bf16x8 bf = __builtin_bit_cast(bf16x8, bu);
        #pragma unroll
        for (int mf = 0; mf < MF; mf++) {
            u16x8 au = *(const u16x8*)(X + (size_t)(mf * 16 + rowa) * K + k + koff);
            acc[mf] = __builtin_amdgcn_mfma_f32_16x16x32_bf16(
                __builtin_bit_cast(bf16x8, au), bf, acc[mf], 0, 0, 0);
        }
    }

    __syncthreads();   // LDS may have been used just before
    #pragma unroll
    for (int mf = 0; mf < MF; mf++)
        #pragma unroll
        for (int i = 0; i < 4; i++)
            red[wave][lane][mf * 4 + i] = acc[mf][i];
    __syncthreads();

    int lane2 = tid & 63, sg = (tid >> 6) & 3, nf2 = tid >> 8;
    int n2 = bx * 32 + nf2 * 16 + (lane2 & 15);
    float b = bias ? bias[n2] : 0.f;
    #pragma unroll
    for (int mf = 0; mf < MF; mf++) {
        int slot = mf * 4 + sg;
        float s = red[0 + nf2][lane2][slot] + red[2 + nf2][lane2][slot]
                + red[4 + nf2][lane2][slot] + red[6 + nf2][lane2][slot] + b;
        int row = mf * 16 + (lane2 >> 4) * 4 + sg;
        size_t o = (size_t)row * N + n2;
        if (outf) outf[o] = s;
        if (outb) outb[o] = f2bf(s);
    }
    __syncthreads();
}

// G[c2,j] = sum_c cls[c,j] * W_ml[c2, c*1024 + (j>>3)]; 512 threads; 80KB LDS
__device__ __forceinline__ void g_role(int idx, const float* __restrict__ cls,
                                       const float* __restrict__ W_ml,
                                       float* __restrict__ G, float* smem) {
    float (*wml)[80][16] = (float (*)[80][16])smem;   // [16][80][16]
    int o0 = (idx & 63) * 16;
    int c2b = (idx >> 6) * 16;
    int j0 = o0 * 8;
    for (int i = threadIdx.x; i < 16 * 80 * 16; i += 512) {
        int ol = i & 15, c = (i >> 4) % 80, c2 = i / 1280;
        wml[c2][c][ol] = W_ml[(size_t)(c2b + c2) * 81920 + c * 1024 + o0 + ol];
    }
    __syncthreads();
    int jl = threadIdx.x & 127;
    int c2l = (threadIdx.x >> 7) * 4;
    int ol = jl >> 3;
    float acc[4] = {0.f, 0.f, 0.f, 0.f};
    for (int c = 0; c < 80; c++) {
        float cv = cls[(size_t)c * 8192 + j0 + jl];
        #pragma unroll
        for (int i = 0; i < 4; i++) acc[i] = fmaf(cv, wml[c2l + i][c][ol], acc[i]);
    }
    #pragma unroll
    for (int i = 0; i < 4; i++) G[(size_t)(c2b + c2l + i) * 8192 + j0 + jl] = acc[i];
    __syncthreads();
}

// out[b,c2] = sum_j img[b,j]*G[c2,j] + b_ml[c2]; unit = btile(16) x cg(10)
__device__ __forceinline__ void out_role(int unit, const float* __restrict__ img,
                                         const float* __restrict__ G,
                                         const float* __restrict__ b_ml,
                                         float* __restrict__ out, float* smem) {
    float (*sm)[32] = (float (*)[32])smem;
    int btile = unit & 15, cg = unit >> 4;
    int kc = threadIdx.x >> 6, lane = threadIdx.x & 63;
    float acc[4][8];
    #pragma unroll
    for (int q = 0; q < 4; q++)
        #pragma unroll
        for (int i = 0; i < 8; i++) acc[q][i] = 0.f;

    #pragma unroll
    for (int step = 0; step < 4; step++) {
        int k = kc * 1024 + step * 256 + lane * 4;
        float4 gv[8];
        #pragma unroll
        for (int i = 0; i < 8; i++) gv[i] = *(const float4*)(G + (size_t)(cg * 8 + i) * 8192 + k);
        #pragma unroll
        for (int q = 0; q < 4; q++) {
            float4 iv = *(const float4*)(img + (size_t)(btile * 4 + q) * 8192 + k);
            #pragma unroll
            for (int i = 0; i < 8; i++) {
                acc[q][i] = fmaf(iv.x, gv[i].x, acc[q][i]);
                acc[q][i] = fmaf(iv.y, gv[i].y, acc[q][i]);
                acc[q][i] = fmaf(iv.z, gv[i].z, acc[q][i]);
                acc[q][i] = fmaf(iv.w, gv[i].w, acc[q][i]);
            }
        }
    }
    #pragma unroll
    for (int q = 0; q < 4; q++)
        #pragma unroll
        for (int i = 0; i < 8; i++) {
            float v = acc[q][i];
            #pragma unroll
            for (int off = 32; off; off >>= 1) v += __shfl_xor(v, off);
            if (lane == 0) sm[kc][q * 8 + i] = v;
        }
    __syncthreads();
    if (threadIdx.x < 32) {
        int i = threadIdx.x & 7;
        float s = b_ml[cg * 8 + i];
        #pragma unroll
        for (int kk = 0; kk < 8; kk++) s += sm[kk][threadIdx.x];
        int q = threadIdx.x >> 3;
        out[(size_t)(btile * 4 + q) * 80 + cg * 8 + i] = s;
    }
}

// =================== THE single mega-kernel ===================
// grid 256 x 512 threads; 6 grid barriers; img GEMM runs as background work
// on blocks idle during the tiny GCN phases.
__global__ __launch_bounds__(512, 2) void mega(
    const float* __restrict__ feature, const float* __restrict__ inp,
    const float* __restrict__ A,       const float* __restrict__ W_gc1,
    const float* __restrict__ W_gc2,   const float* __restrict__ W_img,
    const float* __restrict__ b_img,   const float* __restrict__ W_cls,
    const float* __restrict__ b_cls,   const float* __restrict__ W_ml,
    const float* __restrict__ b_ml,
    unsigned short* featb, float* adjp, float* y0, float* x1,
    unsigned short* x2b, float* wg2t, unsigned short* xb,
    float* img, float* cls, float* G, float* out, unsigned* cnt)
{
    __shared__ __align__(16) float smem[20480];   // 80 KiB union for all roles
    const int bid = blockIdx.x;

    // ---- P0: maxpool(all) + transpose(2 tiles/blk) + y0(0-159) + adj(160) ----
    #pragma unroll
    for (int it = 0; it < 4; ++it) maxpool_role(bid * 4 + it, feature, featb);
    for (int tile = 0; tile < 2; ++tile) {
        __syncthreads();
        transpose_role(bid * 2 + tile, W_gc2, wg2t, smem);
    }
    __syncthreads();
    if (bid < 160)       skinny_role<75>(bid, inp, W_gc1, y0, nullptr, 0, (float4*)smem);
    else if (bid == 160) adj_role(A, adjp, smem);
    grid_barrier(cnt, 256);

    // ---- P1: x1 = leaky(adj@y0) (0-159) | img units 0-95 (160-255) ----
    if (bid < 160) skinny_role<20>(bid, adjp, y0, x1, nullptr, 1, (float4*)smem);
    else gemm_block<4>(bid - 160, featb, W_img, b_img, img, nullptr, 8192, 2048,
                       (float (*)[64][21])smem);
    grid_barrier(cnt, 512);

    // ---- P2: x2b = adj@x1 (0-159) | img units 96-191 (160-255) ----
    if (bid < 160) skinny_role<20>(bid, adjp, x1, nullptr, x2b, 0, (float4*)smem);
    else gemm_block<4>(bid - 160 + 96, featb, W_img, b_img, img, nullptr, 8192, 2048,
                       (float (*)[64][21])smem);
    grid_barrier(cnt, 768);

    // ---- P3: xb = x2 @ wg2t (0-63) | img units 192-255 (64-127) ----
    if (bid < 64)
        gemm_block<5>(bid, x2b, wg2t, nullptr, nullptr, xb, 2048, 1024,
                      (float (*)[64][21])smem);
    else if (bid < 128)
        gemm_block<4>(bid - 64 + 192, featb, W_img, b_img, img, nullptr, 8192, 2048,
                      (float (*)[64][21])smem);
    grid_barrier(cnt, 1024);

    // ---- P4: cls = xb @ W_cls^T + b_cls (all 256) ----
    gemm_block<5>(bid, xb, W_cls, b_cls, cls, nullptr, 8192, 2048,
                  (float (*)[64][21])smem);
    grid_barrier(cnt, 1280);

    // ---- P5: G (320 units over 256 blocks) ----
    g_role(bid, cls, W_ml, G, smem);
    if (bid < 64) g_role(256 + bid, cls, W_ml, G, smem);
    grid_barrier(cnt, 1536);

    // ---- P6: out (160 units) ----
    if (bid < 160) out_role(bid, img, G, b_ml, out, smem);
}

// ---------------- launch ----------------
extern "C" void kernel_launch(void* const* d_in, const int* in_sizes, int n_in,
                              void* d_out, int out_size, void* d_ws, size_t ws_size,
                              hipStream_t stream) {
    (void)in_sizes; (void)n_in; (void)out_size; (void)ws_size;
    const float* feature = (const float*)d_in[0];
    const float* inp     = (const float*)d_in[1];
    const float* A       = (const float*)d_in[2];
    const float* W_gc1   = (const float*)d_in[3];
    const float* W_gc2   = (const float*)d_in[4];
    const float* W_img   = (const float*)d_in[5];
    const float* b_img   = (const float*)d_in[6];
    const float* W_cls   = (const float*)d_in[7];
    const float* b_cls   = (const float*)d_in[8];
    const float* W_ml    = (const float*)d_in[9];
    const float* b_ml    = (const float*)d_in[10];
    float* out = (float*)d_out;
    char*  ws  = (char*)d_ws;

    unsigned short* featb = (unsigned short*)(ws + OFF_FEATB);
    float* adjp = (float*)(ws + OFF_ADJ);
    float* y0   = (float*)(ws + OFF_Y0);
    float* x1   = (float*)(ws + OFF_X1);
    unsigned short* x2b = (unsigned short*)(ws + OFF_X2B);
    float* wg2t = (float*)(ws + OFF_WG2T);
    unsigned short* xb  = (unsigned short*)(ws + OFF_XB);
    float* img  = (float*)(ws + OFF_IMG);
    float* cls  = (float*)(ws + OFF_CLS);
    float* G    = (float*)(ws + OFF_G);
    unsigned* cnt = (unsigned*)(ws + OFF_CNT);

    hipMemsetAsync(cnt, 0, 4, stream);   // barrier counter = 0 each call (captured)
    mega<<<256, 512, 0, stream>>>(feature, inp, A, W_gc1, W_gc2, W_img, b_img,
                                  W_cls, b_cls, W_ml, b_ml,
                                  featb, adjp, y0, x1, x2b, wg2t, xb,
                                  img, cls, G, out, cnt);
}

// Round 6
// 261.847 us; speedup vs baseline: 1.8720x; 1.8720x over previous
//
#include <hip/hip_runtime.h>
#include <hip/hip_bf16.h>
#include <cstdint>
#include <cstddef>

// ---------------- types / helpers ----------------
typedef float  f32x4  __attribute__((ext_vector_type(4)));
typedef __bf16 bf16x8 __attribute__((ext_vector_type(8)));
typedef unsigned short u16x8 __attribute__((ext_vector_type(8)));

__device__ __forceinline__ unsigned short f2bf(float f) {
    unsigned u = __float_as_uint(f);
    u += 0x7FFFu + ((u >> 16) & 1u);   // round-to-nearest-even
    return (unsigned short)(u >> 16);
}

// ---------------- problem constants ----------------
// B=64, C=80, IN_CH=300, J=8192, S=8, OUT=1024
// feature [64,2048,14,14] (131072 rows of 196), out [64,80]

// ---------------- ws layout (bytes) ----------------
constexpr size_t OFF_FEATB = 0;          // 64*2048 bf16  = 262144
constexpr size_t OFF_X2B   = 262144;     // 80*1024 bf16  = 163840
constexpr size_t OFF_WG2T  = 425984;     // 2048*1024 f32 = 8388608
constexpr size_t OFF_XB    = 8814592;    // 80*2048 bf16  = 327680
constexpr size_t OFF_IMG   = 9142272;    // 64*8192 f32   = 2097152
constexpr size_t OFF_CLS   = 11239424;   // 80*8192 f32   = 2621440
constexpr size_t OFF_G     = 13860864;   // 80*8192 f32   = 2621440
constexpr size_t OFF_CNT   = 16482304;   // 4 bytes barrier counter

// ---------------- grid-wide barrier (relaxed spin!) ----------------
// Grid = 256 blocks, 1-2 blocks/CU capacity -> all co-resident, spin is safe.
// CRITICAL: poll with RELAXED load; acquire-fence ONCE after exit. An acquire
// load in the loop emits a whole-L2 buffer_inv per iteration (round-4 bug).
__device__ __forceinline__ void grid_barrier(unsigned* cnt, unsigned target) {
    __syncthreads();
    if (threadIdx.x == 0) {
        __builtin_amdgcn_fence(__ATOMIC_RELEASE, "agent");
        __hip_atomic_fetch_add(cnt, 1u, __ATOMIC_RELAXED, __HIP_MEMORY_SCOPE_AGENT);
        while (__hip_atomic_load(cnt, __ATOMIC_RELAXED, __HIP_MEMORY_SCOPE_AGENT) < target)
            __builtin_amdgcn_s_sleep(8);
        __builtin_amdgcn_fence(__ATOMIC_ACQUIRE, "agent");
    }
    __syncthreads();
}

// =================== roles (device functions) ===================

// maxpool: 16 lanes per row, 4 rows per wave, 128 rows per virtual bid.
__device__ __forceinline__ void maxpool_role(int vbid, const float* __restrict__ feature,
                                             unsigned short* __restrict__ featb) {
    int wave = threadIdx.x >> 6, lane = threadIdx.x & 63;
    int r = lane >> 4, q = lane & 15;
    int row = vbid * 128 + wave * 4 + r;          // 8 waves x 4 rows = 32 rows
    #pragma unroll
    for (int it = 0; it < 4; ++it) {              // x4 = 128 rows
        int rr = row + it * 32;
        const float4* p = (const float4*)(feature + (size_t)rr * 196);
        float4 a = p[q], b = p[q + 16], c = p[q + 32];
        float m = fmaxf(fmaxf(fmaxf(a.x, a.y), fmaxf(a.z, a.w)),
                 fmaxf(fmaxf(fmaxf(b.x, b.y), fmaxf(b.z, b.w)),
                       fmaxf(fmaxf(c.x, c.y), fmaxf(c.z, c.w))));
        if (q == 0) {                             // tail float4 (192..195)
            float4 d = p[48];
            m = fmaxf(m, fmaxf(fmaxf(d.x, d.y), fmaxf(d.z, d.w)));
        }
        #pragma unroll
        for (int off = 1; off < 16; off <<= 1) m = fmaxf(m, __shfl_xor(m, off));
        if (q == 0) featb[rr] = f2bf(m);
    }
}

// fully-fused GCN front: this block owns 16 columns (j0 = idx*16) and computes
// y0, x1=leaky(adj@y0), x2=adj@x1 for its slice, all in LDS. No cross-block deps.
__device__ __forceinline__ void gcn_fused_role(int idx, const float* __restrict__ inp,
                                               const float* __restrict__ W1,
                                               const float* __restrict__ A,
                                               unsigned short* __restrict__ x2b,
                                               float* smem) {
    float* adjs = smem;           // [80][80]  25.6 KB
    float* y0s  = smem + 6400;    // [80][16]  5 KB
    float* x1s  = smem + 7680;    // [80][16]  5 KB
    float* dinv = smem + 8960;    // [80]
    int t = threadIdx.x;
    int j0 = idx * 16;
    int j = t & 15, kbase = t >> 4;               // kbase 0..31

    if (t < 80) {
        const float4* ar = (const float4*)(A + t * 80);
        float4 s4 = {0.f, 0.f, 0.f, 0.f};
        #pragma unroll
        for (int q = 0; q < 20; q++) {
            float4 v = ar[q];
            s4.x += v.x; s4.y += v.y; s4.z += v.z; s4.w += v.w;
        }
        dinv[t] = 1.0f / sqrtf(s4.x + s4.y + s4.z + s4.w);
    }
    __syncthreads();
    for (int i = t; i < 6400; i += 512) {
        int r = i / 80, cc = i % 80;
        adjs[i] = A[cc * 80 + r] * dinv[r] * dinv[cc];
    }

    // y0[k, j0+j] = sum_e inp[k,e] * W1[e, j0+j]   (k = kbase + 32*it)
    float accs[3];
    #pragma unroll
    for (int it = 0; it < 3; ++it) {
        int k = kbase + it * 32;
        float acc = 0.f;
        if (k < 80) {
            const float* ir = inp + k * 300;
            const float* wc = W1 + j0 + j;
            #pragma unroll 4
            for (int e = 0; e < 300; e++) acc = fmaf(ir[e], wc[(size_t)e * 1024], acc);
        }
        accs[it] = acc;
    }
    __syncthreads();                               // adjs complete
    #pragma unroll
    for (int it = 0; it < 3; ++it) {
        int k = kbase + it * 32;
        if (k < 80) y0s[k * 16 + j] = accs[it];
    }
    __syncthreads();                               // y0s visible

    #pragma unroll
    for (int it = 0; it < 3; ++it) {
        int c = kbase + it * 32;
        if (c < 80) {
            float acc = 0.f;
            #pragma unroll 4
            for (int k = 0; k < 80; k++) acc = fmaf(adjs[c * 80 + k], y0s[k * 16 + j], acc);
            if (acc < 0.f) acc *= 0.2f;
            x1s[c * 16 + j] = acc;
        }
    }
    __syncthreads();                               // x1s visible

    #pragma unroll
    for (int it = 0; it < 3; ++it) {
        int c = kbase + it * 32;
        if (c < 80) {
            float acc = 0.f;
            #pragma unroll 4
            for (int k = 0; k < 80; k++) acc = fmaf(adjs[c * 80 + k], x1s[k * 16 + j], acc);
            x2b[c * 1024 + j0 + j] = f2bf(acc);
        }
    }
}

// transpose W_gc2 [1024][2048] -> wg2t [2048][1024], 64x64 tiles, 512 threads
__device__ __forceinline__ void transpose_role(int idx, const float* __restrict__ in,
                                               float* __restrict__ out, float* t /*64*65*/) {
    int c0 = (idx & 31) * 64, r0 = (idx >> 5) * 64;
    int tx = threadIdx.x & 63, ty = threadIdx.x >> 6;   // 64 x 8
    #pragma unroll
    for (int i = 0; i < 64; i += 8)
        t[(ty + i) * 65 + tx] = in[(size_t)(r0 + ty + i) * 2048 + c0 + tx];
    __syncthreads();
    #pragma unroll
    for (int i = 0; i < 64; i += 8)
        out[(size_t)(c0 + ty + i) * 1024 + r0 + tx] = t[tx * 65 + (ty + i)];
}

// MFMA GEMM with in-block K-split: out[m,n] = sum_k X[m,k]*W[n,k] (+bias[n])
// block = 8 waves: 2 n-frags x 4 k-splits; BN=32; LDS reduce; f32/bf16 out.
template <int MF>
__device__ __forceinline__ void gemm_block(int bx, const unsigned short* __restrict__ X,
                                           const float* __restrict__ W,
                                           const float* __restrict__ bias,
                                           float* __restrict__ outf,
                                           unsigned short* __restrict__ outb,
                                           int N, int K, float (*red)[64][21]) {
    int tid = threadIdx.x;
    int wave = tid >> 6, lane = tid & 63;
    int nf = wave & 1, ks = wave >> 1;
    int n = bx * 32 + nf * 16 + (lane & 15);
    int rowa = lane & 15;
    int koff = (lane >> 4) * 8;
    int Kc = K >> 2;
    int k0 = ks * Kc;

    f32x4 acc[MF];
    #pragma unroll
    for (int i = 0; i < MF; i++) acc[i] = (f32x4)(0.f);

    const float* wrow = W + (size_t)n * K;

    #pragma unroll 2
    for (int k = k0; k < k0 + Kc; k += 32) {
        float4 w0 = *(const float4*)(wrow + k + koff);
        float4 w1 = *(const float4*)(wrow + k + koff + 4);
        u16x8 bu;
        bu[0] = f2bf(w0.x); bu[1] = f2bf(w0.y); bu[2] = f2bf(w0.z); bu[3] = f2bf(w0.w);
        bu[4] = f2bf(w1.x); bu[5] = f2bf(w1.y); bu[6] = f2bf(w1.z); bu[7] = f2bf(w1.w);
        bf16x8 bf = __builtin_bit_cast(bf16x8, bu);
        #pragma unroll
        for (int mf = 0; mf < MF; mf++) {
            u16x8 au = *(const u16x8*)(X + (size_t)(mf * 16 + rowa) * K + k + koff);
            acc[mf] = __builtin_amdgcn_mfma_f32_16x16x32_bf16(
                __builtin_bit_cast(bf16x8, au), bf, acc[mf], 0, 0, 0);
        }
    }

    __syncthreads();   // LDS may be in use from a previous role
    #pragma unroll
    for (int mf = 0; mf < MF; mf++)
        #pragma unroll
        for (int i = 0; i < 4; i++)
            red[wave][lane][mf * 4 + i] = acc[mf][i];
    __syncthreads();

    int lane2 = tid & 63, sg = (tid >> 6) & 3, nf2 = tid >> 8;
    int n2 = bx * 32 + nf2 * 16 + (lane2 & 15);
    float b = bias ? bias[n2] : 0.f;
    #pragma unroll
    for (int mf = 0; mf < MF; mf++) {
        int slot = mf * 4 + sg;
        float s = red[0 + nf2][lane2][slot] + red[2 + nf2][lane2][slot]
                + red[4 + nf2][lane2][slot] + red[6 + nf2][lane2][slot] + b;
        int row = mf * 16 + (lane2 >> 4) * 4 + sg;
        size_t o = (size_t)row * N + n2;
        if (outf) outf[o] = s;
        if (outb) outb[o] = f2bf(s);
    }
    __syncthreads();
}

// G[c2,j] = sum_c cls[c,j] * W_ml[c2, c*1024 + (j>>3)]; 512 threads; 80KB LDS
__device__ __forceinline__ void g_role(int idx, const float* __restrict__ cls,
                                       const float* __restrict__ W_ml,
                                       float* __restrict__ G, float* smem) {
    float (*wml)[80][16] = (float (*)[80][16])smem;   // [16][80][16]
    int o0 = (idx & 63) * 16;
    int c2b = (idx >> 6) * 16;
    int j0 = o0 * 8;
    __syncthreads();
    for (int i = threadIdx.x; i < 16 * 80 * 16; i += 512) {
        int ol = i & 15, c = (i >> 4) % 80, c2 = i / 1280;
        wml[c2][c][ol] = W_ml[(size_t)(c2b + c2) * 81920 + c * 1024 + o0 + ol];
    }
    __syncthreads();
    int jl = threadIdx.x & 127;
    int c2l = (threadIdx.x >> 7) * 4;
    int ol = jl >> 3;
    float acc[4] = {0.f, 0.f, 0.f, 0.f};
    for (int c = 0; c < 80; c++) {
        float cv = cls[(size_t)c * 8192 + j0 + jl];
        #pragma unroll
        for (int i = 0; i < 4; i++) acc[i] = fmaf(cv, wml[c2l + i][c][ol], acc[i]);
    }
    #pragma unroll
    for (int i = 0; i < 4; i++) G[(size_t)(c2b + c2l + i) * 8192 + j0 + jl] = acc[i];
    __syncthreads();
}

// out[b,c2] = sum_j img[b,j]*G[c2,j] + b_ml[c2]; unit = btile(16) x cg(10)
__device__ __forceinline__ void out_role(int unit, const float* __restrict__ img,
                                         const float* __restrict__ G,
                                         const float* __restrict__ b_ml,
                                         float* __restrict__ out, float* smem) {
    float (*sm)[32] = (float (*)[32])smem;
    int btile = unit & 15, cg = unit >> 4;
    int kc = threadIdx.x >> 6, lane = threadIdx.x & 63;
    float acc[4][8];
    #pragma unroll
    for (int q = 0; q < 4; q++)
        #pragma unroll
        for (int i = 0; i < 8; i++) acc[q][i] = 0.f;

    #pragma unroll
    for (int step = 0; step < 4; step++) {
        int k = kc * 1024 + step * 256 + lane * 4;
        float4 gv[8];
        #pragma unroll
        for (int i = 0; i < 8; i++) gv[i] = *(const float4*)(G + (size_t)(cg * 8 + i) * 8192 + k);
        #pragma unroll
        for (int q = 0; q < 4; q++) {
            float4 iv = *(const float4*)(img + (size_t)(btile * 4 + q) * 8192 + k);
            #pragma unroll
            for (int i = 0; i < 8; i++) {
                acc[q][i] = fmaf(iv.x, gv[i].x, acc[q][i]);
                acc[q][i] = fmaf(iv.y, gv[i].y, acc[q][i]);
                acc[q][i] = fmaf(iv.z, gv[i].z, acc[q][i]);
                acc[q][i] = fmaf(iv.w, gv[i].w, acc[q][i]);
            }
        }
    }
    #pragma unroll
    for (int q = 0; q < 4; q++)
        #pragma unroll
        for (int i = 0; i < 8; i++) {
            float v = acc[q][i];
            #pragma unroll
            for (int off = 32; off; off >>= 1) v += __shfl_xor(v, off);
            if (lane == 0) sm[kc][q * 8 + i] = v;
        }
    __syncthreads();
    if (threadIdx.x < 32) {
        int i = threadIdx.x & 7;
        float s = b_ml[cg * 8 + i];
        #pragma unroll
        for (int kk = 0; kk < 8; kk++) s += sm[kk][threadIdx.x];
        int q = threadIdx.x >> 3;
        out[(size_t)(btile * 4 + q) * 80 + cg * 8 + i] = s;
    }
}

// =================== THE single mega-kernel, 4 barriers ===================
__global__ __launch_bounds__(512, 2) void mega(
    const float* __restrict__ feature, const float* __restrict__ inp,
    const float* __restrict__ A,       const float* __restrict__ W_gc1,
    const float* __restrict__ W_gc2,   const float* __restrict__ W_img,
    const float* __restrict__ b_img,   const float* __restrict__ W_cls,
    const float* __restrict__ b_cls,   const float* __restrict__ W_ml,
    const float* __restrict__ b_ml,
    unsigned short* featb, unsigned short* x2b, float* wg2t,
    unsigned short* xb, float* img, float* cls, float* G,
    float* out, unsigned* cnt)
{
    __shared__ __align__(16) float smem[20480];   // 80 KiB union for all roles
    const int bid = blockIdx.x;

    // ---- P0: gcn-fused(0-63) | transpose(64-95, 16 tiles ea) | maxpool(96-255) ----
    if (bid < 64) {
        gcn_fused_role(bid, inp, W_gc1, A, x2b, smem);
    } else if (bid < 96) {
        for (int tile = bid - 64; tile < 512; tile += 32) {
            __syncthreads();
            transpose_role(tile, W_gc2, wg2t, smem);
        }
    } else {
        for (int v = bid - 96; v < 1024; v += 160)
            maxpool_role(v, feature, featb);
    }
    grid_barrier(cnt, 256);

    // ---- P1: xb = x2 @ wg2t (0-63) | img units 0-191 (64-255) ----
    if (bid < 64)
        gemm_block<5>(bid, x2b, wg2t, nullptr, nullptr, xb, 2048, 1024,
                      (float (*)[64][21])smem);
    else
        gemm_block<4>(bid - 64, featb, W_img, b_img, img, nullptr, 8192, 2048,
                      (float (*)[64][21])smem);
    grid_barrier(cnt, 512);

    // ---- P2: img units 192-255 (0-63, first) then cls unit bid (all) ----
    if (bid < 64)
        gemm_block<4>(192 + bid, featb, W_img, b_img, img, nullptr, 8192, 2048,
                      (float (*)[64][21])smem);
    gemm_block<5>(bid, xb, W_cls, b_cls, cls, nullptr, 8192, 2048,
                  (float (*)[64][21])smem);
    grid_barrier(cnt, 768);

    // ---- P3: G (320 units over 256 blocks) ----
    g_role(bid, cls, W_ml, G, smem);
    if (bid < 64) g_role(256 + bid, cls, W_ml, G, smem);
    grid_barrier(cnt, 1024);

    // ---- P4: out (160 units) ----
    if (bid < 160) out_role(bid, img, G, b_ml, out, smem);
}

// ---------------- launch ----------------
extern "C" void kernel_launch(void* const* d_in, const int* in_sizes, int n_in,
                              void* d_out, int out_size, void* d_ws, size_t ws_size,
                              hipStream_t stream) {
    (void)in_sizes; (void)n_in; (void)out_size; (void)ws_size;
    const float* feature = (const float*)d_in[0];
    const float* inp     = (const float*)d_in[1];
    const float* A       = (const float*)d_in[2];
    const float* W_gc1   = (const float*)d_in[3];
    const float* W_gc2   = (const float*)d_in[4];
    const float* W_img   = (const float*)d_in[5];
    const float* b_img   = (const float*)d_in[6];
    const float* W_cls   = (const float*)d_in[7];
    const float* b_cls   = (const float*)d_in[8];
    const float* W_ml    = (const float*)d_in[9];
    const float* b_ml    = (const float*)d_in[10];
    float* out = (float*)d_out;
    char*  ws  = (char*)d_ws;

    unsigned short* featb = (unsigned short*)(ws + OFF_FEATB);
    unsigned short* x2b   = (unsigned short*)(ws + OFF_X2B);
    float* wg2t = (float*)(ws + OFF_WG2T);
    unsigned short* xb    = (unsigned short*)(ws + OFF_XB);
    float* img  = (float*)(ws + OFF_IMG);
    float* cls  = (float*)(ws + OFF_CLS);
    float* G    = (float*)(ws + OFF_G);
    unsigned* cnt = (unsigned*)(ws + OFF_CNT);

    (void)hipMemsetAsync(cnt, 0, 4, stream);   // barrier counter = 0 (captured)
    mega<<<256, 512, 0, stream>>>(feature, inp, A, W_gc1, W_gc2, W_img, b_img,
                                  W_cls, b_cls, W_ml, b_ml,
                                  featb, x2b, wg2t, xb, img, cls, G, out, cnt);
}